// Round 12
// baseline (252.996 us; speedup 1.0000x reference)
//
#include <hip/hip_runtime.h>
#include <hip/hip_bf16.h>

// ---------------------------------------------------------------------------
// CGNN: 2 layers of { m = h[src]*e ; s = segment_mean(m,dst) ;
//                     [h, h_N] @ W + b (+ relu on layer 1) }
// Round 11: fused per-layer kernel (agg -> LDS -> linear).
//   - reorder chain unchanged except bucket_sort stores PRE-SCALED byte
//     offsets (src*128) in-place (compact CSR — r10 padding reverted).
//   - gnn_layer_kernel: block = 64 nodes x 4 waves.
//       A: stage h-half of xin (coalesced, fp32 or bf16 per layer)
//       B: wave wv aggregates nodes [wv*16, wv*16+16): r9's masked
//          16-edge-in-flight bf16 gather, result written to xin s-half (LDS)
//       C: linear phase (4 waves split OUT cols, W via s_load)
//     Global s buffer eliminated (~100 MB traffic); 2 fewer dispatches/layer.
//   - two bf16 shadow tables: hb0 = in_feat, hb1 = h1 (no gather/write race).
// ---------------------------------------------------------------------------

#define F 64
#define NBMAX 2048          // bucket arrays sized for up to 2048 buckets
#define EPT 8               // edges per thread in hist/multisplit
#define TPB 1024            // threads per block in hist/multisplit
#define EPB (EPT * TPB)     // edges per block = 8192
#define BSMAX 2048          // max records per bucket staged in LDS

__global__ __launch_bounds__(TPB) void bhist_kernel(
    const int* __restrict__ dst, int* __restrict__ bcnt, int n_edges, int nb)
{
    __shared__ int lcnt[NBMAX];
    const int tid = threadIdx.x;
    for (int i = tid; i < nb; i += TPB) lcnt[i] = 0;
    __syncthreads();

    const int e0 = blockIdx.x * EPB + tid;
#pragma unroll
    for (int k = 0; k < EPT; ++k) {
        const int e = e0 + k * TPB;
        if (e < n_edges) atomicAdd(&lcnt[dst[e] >> 6], 1);
    }
    __syncthreads();
    for (int i = tid; i < nb; i += TPB) {
        const int c = lcnt[i];
        if (c) atomicAdd(&bcnt[i], c);
    }
}

// Single block: exclusive scan of bcnt into boff (nb+1 entries) + bcursor.
__global__ __launch_bounds__(1024) void scan_kernel(
    const int* __restrict__ bcnt, int* __restrict__ boff,
    int* __restrict__ bcursor, int nb)
{
    __shared__ int wsum[16];
    __shared__ int carry_s;
    const int tid = threadIdx.x;
    if (tid == 0) carry_s = 0;
    __syncthreads();

    for (int c0 = 0; c0 < nb; c0 += 1024) {
        const int i = c0 + tid;
        const int c = (i < nb) ? bcnt[i] : 0;
        int v = c;
        for (int d = 1; d < 64; d <<= 1) {
            int t = __shfl_up(v, d, 64);
            if ((tid & 63) >= d) v += t;
        }
        const int wid = tid >> 6;
        if ((tid & 63) == 63) wsum[wid] = v;
        __syncthreads();
        if (tid < 16) {
            int t = wsum[tid];
            for (int d = 1; d < 16; d <<= 1) {
                int u = __shfl_up(t, d, 16);
                if (tid >= d) t += u;
            }
            wsum[tid] = t;
        }
        __syncthreads();
        const int carry = carry_s;
        const int incl  = carry + ((wid > 0) ? wsum[wid - 1] : 0) + v;
        if (i < nb) {
            boff[i + 1] = incl;
            bcursor[i]  = incl - c;
            if (i == 0) boff[0] = 0;
        }
        __syncthreads();
        if (tid == 1023) carry_s = incl;
        __syncthreads();
    }
}

// Block-local multisplit: rank 8192 edges in LDS, reserve per-bucket ranges
// with one global atomic per non-empty bucket, write dense per-bucket runs.
// rec.x = (local_dst << 20) | src,  rec.y = bits(edge_feat).
__global__ __launch_bounds__(TPB) void multisplit_kernel(
    const int* __restrict__ src, const int* __restrict__ dst,
    const float* __restrict__ ef, int* __restrict__ bcursor,
    int2* __restrict__ brec, int n_edges, int nb)
{
    __shared__ int lcnt[NBMAX];
    __shared__ int lbase[NBMAX];
    const int tid = threadIdx.x;
    for (int i = tid; i < nb; i += TPB) lcnt[i] = 0;
    __syncthreads();

    const int e0 = blockIdx.x * EPB + tid;
    int d[EPT], rk[EPT];
#pragma unroll
    for (int k = 0; k < EPT; ++k) {
        const int e = e0 + k * TPB;
        const int dd = (e < n_edges) ? dst[e] : -1;
        d[k]  = dd;
        rk[k] = (dd >= 0) ? atomicAdd(&lcnt[dd >> 6], 1) : 0;
    }
    __syncthreads();
    for (int i = tid; i < nb; i += TPB) {
        const int c = lcnt[i];
        lbase[i] = c ? atomicAdd(&bcursor[i], c) : 0;
    }
    __syncthreads();
#pragma unroll
    for (int k = 0; k < EPT; ++k) {
        const int e = e0 + k * TPB;
        if (e < n_edges) {
            const int dd  = d[k];
            const int pos = lbase[dd >> 6] + rk[k];
            brec[pos] = make_int2(((dd & 63) << 20) | src[e],
                                  __float_as_int(ef[e]));
        }
    }
}

// Block per bucket: stage records in LDS, 64-counter histogram + wave scan,
// write back IN PLACE at exact per-node positions (contiguous window).
// Final records carry PRE-SCALED byte offsets (src*128).
// Emits off2 (n_nodes+1) and invdeg.
__global__ __launch_bounds__(256) void bucket_sort_kernel(
    int2* __restrict__ brec, const int* __restrict__ boff,
    int* __restrict__ off2, float* __restrict__ invdeg, int n_nodes, int nb)
{
    __shared__ int2 stage[BSMAX];
    __shared__ int  lcnt[64];
    __shared__ int  lcur[64];

    const int b   = blockIdx.x;
    const int tid = threadIdx.x;
    const int e0  = boff[b];
    const int e1  = boff[b + 1];
    const int cnt = e1 - e0;

    if (tid < 64) lcnt[tid] = 0;
    __syncthreads();

    for (int i = tid; i < cnt; i += 256) {
        const int2 r = brec[e0 + i];
        stage[i] = r;
        atomicAdd(&lcnt[r.x >> 20], 1);
    }
    __syncthreads();

    if (tid < 64) {
        const int c = lcnt[tid];
        int v = c;
        for (int d = 1; d < 64; d <<= 1) {
            int t = __shfl_up(v, d, 64);
            if (tid >= d) v += t;
        }
        const int excl = v - c;
        lcur[tid] = excl;
        const int node = (b << 6) + tid;
        if (node < n_nodes) {
            off2[node]   = e0 + excl;
            invdeg[node] = 1.0f / fmaxf((float)c, 1.0f);
        }
    }
    if (tid == 0 && b == nb - 1) off2[n_nodes] = e1;
    __syncthreads();

    for (int i = tid; i < cnt; i += 256) {
        const int2 r   = stage[i];
        const int  pos = atomicAdd(&lcur[r.x >> 20], 1);
        brec[e0 + pos] = make_int2((r.x & 0xFFFFF) << 7, r.y);  // byte offset
    }
}

__device__ __forceinline__ unsigned bf16_rne(float f)
{
    unsigned u = __float_as_uint(f);
    return (u + 0x7FFFu + ((u >> 16) & 1u)) >> 16;
}

// RNE-convert fp32 array to packed bf16 (8 elems / thread).
__global__ __launch_bounds__(256) void f32_to_bf16_kernel(
    const float* __restrict__ x, unsigned short* __restrict__ y, int n8)
{
    const int i = blockIdx.x * 256 + threadIdx.x;
    if (i >= n8) return;
    const float4 a = ((const float4*)x)[2 * i];
    const float4 b = ((const float4*)x)[2 * i + 1];
    uint4 o;
    o.x = bf16_rne(a.x) | (bf16_rne(a.y) << 16);
    o.y = bf16_rne(a.z) | (bf16_rne(a.w) << 16);
    o.z = bf16_rne(b.x) | (bf16_rne(b.y) << 16);
    o.w = bf16_rne(b.z) | (bf16_rne(b.w) << 16);
    ((uint4*)y)[i] = o;
}

// Fused GNN layer. Block = 64 nodes x 4 waves.
//   A: stage h-half of xin (fp32 or bf16 input, coalesced)
//   B: wave wv aggregates nodes [wv*16, ...): masked 16-edge-in-flight
//      bf16 gather from hb_g (byte-offset records), s written to LDS
//   C: linear: wave wv computes cols [wv*JT, ...) for all 64 nodes,
//      x from LDS (ds_read_b128), W via wave-uniform s_load.
template <int OUT, bool RELU, bool IN_BF16, bool OUT_BF16>
__global__ __launch_bounds__(256) void gnn_layer_kernel(
    const float* __restrict__ hin_f, const unsigned short* __restrict__ hin_b,
    const unsigned short* __restrict__ hb_g, const int2* __restrict__ rec,
    const int* __restrict__ off, const float* __restrict__ invdeg,
    const float* __restrict__ W, const float* __restrict__ b,
    float* __restrict__ out, unsigned short* __restrict__ hb_out, int n_nodes)
{
    constexpr int JT  = OUT / 4;
    constexpr int STR = 132;       // row stride in floats (128 + 4)
    __shared__ float xin[64 * STR];

    const int tid   = threadIdx.x;
    const int node0 = blockIdx.x * 64;
    const int lane  = tid & 63;
    const int wv    = tid >> 6;

    // ---- phase A: stage h-half ----
    if constexpr (IN_BF16) {
        for (int i = tid; i < 512; i += 256) {
            const int ln = i >> 3, c8 = i & 7;
            const int node = node0 + ln;
            uint4 v = make_uint4(0u, 0u, 0u, 0u);
            if (node < n_nodes)
                v = *(const uint4*)&hin_b[(size_t)node * F + c8 * 8];
            float4 lo = make_float4(__uint_as_float(v.x << 16),
                                    __uint_as_float(v.x & 0xFFFF0000u),
                                    __uint_as_float(v.y << 16),
                                    __uint_as_float(v.y & 0xFFFF0000u));
            float4 hi = make_float4(__uint_as_float(v.z << 16),
                                    __uint_as_float(v.z & 0xFFFF0000u),
                                    __uint_as_float(v.w << 16),
                                    __uint_as_float(v.w & 0xFFFF0000u));
            *(float4*)&xin[ln * STR + c8 * 8]     = lo;
            *(float4*)&xin[ln * STR + c8 * 8 + 4] = hi;
        }
    } else {
        for (int i = tid; i < 1024; i += 256) {
            const int ln = i >> 4, c4 = i & 15;
            const int node = node0 + ln;
            float4 v = make_float4(0.f, 0.f, 0.f, 0.f);
            if (node < n_nodes)
                v = *(const float4*)&hin_f[(size_t)node * F + c4 * 4];
            *(float4*)&xin[ln * STR + c4 * 4] = v;
        }
    }

    // ---- phase B: aggregate 16 nodes per wave, s -> LDS ----
    const int g = lane >> 3;   // 0..7 edge slot
    const int q = lane & 7;    // 0..7 feature octet
    const char* __restrict__ hq = (const char*)hb_g + q * 16;

    for (int t = 0; t < 16; ++t) {
        const int ln   = (wv << 4) + t;
        const int node = node0 + ln;
        if (node >= n_nodes) break;

        const int e0 = off[node];
        const int e1 = off[node + 1];
        const int niter = (e1 - e0 + 15) >> 4;

        float4 aA0 = make_float4(0.f, 0.f, 0.f, 0.f);
        float4 aA1 = make_float4(0.f, 0.f, 0.f, 0.f);
        float4 aB0 = make_float4(0.f, 0.f, 0.f, 0.f);
        float4 aB1 = make_float4(0.f, 0.f, 0.f, 0.f);

        for (int it = 0; it < niter; ++it) {
            const int  base = e0 + it * 16;
            const int  eA   = base + g;
            const int  eB   = base + 8 + g;
            const bool vA   = eA < e1;
            const bool vB   = eB < e1;
            const int2 rA = rec[vA ? eA : e0];
            const int2 rB = rec[vB ? eB : e0];
            const float evA = vA ? __int_as_float(rA.y) : 0.f;
            const float evB = vB ? __int_as_float(rB.y) : 0.f;
            const uint4 xA = *(const uint4*)(hq + rA.x);
            const uint4 xB = *(const uint4*)(hq + rB.x);

            aA0.x = fmaf(__uint_as_float(xA.x << 16),         evA, aA0.x);
            aA0.y = fmaf(__uint_as_float(xA.x & 0xFFFF0000u), evA, aA0.y);
            aA0.z = fmaf(__uint_as_float(xA.y << 16),         evA, aA0.z);
            aA0.w = fmaf(__uint_as_float(xA.y & 0xFFFF0000u), evA, aA0.w);
            aA1.x = fmaf(__uint_as_float(xA.z << 16),         evA, aA1.x);
            aA1.y = fmaf(__uint_as_float(xA.z & 0xFFFF0000u), evA, aA1.y);
            aA1.z = fmaf(__uint_as_float(xA.w << 16),         evA, aA1.z);
            aA1.w = fmaf(__uint_as_float(xA.w & 0xFFFF0000u), evA, aA1.w);

            aB0.x = fmaf(__uint_as_float(xB.x << 16),         evB, aB0.x);
            aB0.y = fmaf(__uint_as_float(xB.x & 0xFFFF0000u), evB, aB0.y);
            aB0.z = fmaf(__uint_as_float(xB.y << 16),         evB, aB0.z);
            aB0.w = fmaf(__uint_as_float(xB.y & 0xFFFF0000u), evB, aB0.w);
            aB1.x = fmaf(__uint_as_float(xB.z << 16),         evB, aB1.x);
            aB1.y = fmaf(__uint_as_float(xB.z & 0xFFFF0000u), evB, aB1.y);
            aB1.z = fmaf(__uint_as_float(xB.w << 16),         evB, aB1.z);
            aB1.w = fmaf(__uint_as_float(xB.w & 0xFFFF0000u), evB, aB1.w);
        }

        float4 a0 = make_float4(aA0.x + aB0.x, aA0.y + aB0.y,
                                aA0.z + aB0.z, aA0.w + aB0.w);
        float4 a1 = make_float4(aA1.x + aB1.x, aA1.y + aB1.y,
                                aA1.z + aB1.z, aA1.w + aB1.w);

#pragma unroll
        for (int m = 8; m < 64; m <<= 1) {
            a0.x += __shfl_xor(a0.x, m); a0.y += __shfl_xor(a0.y, m);
            a0.z += __shfl_xor(a0.z, m); a0.w += __shfl_xor(a0.w, m);
            a1.x += __shfl_xor(a1.x, m); a1.y += __shfl_xor(a1.y, m);
            a1.z += __shfl_xor(a1.z, m); a1.w += __shfl_xor(a1.w, m);
        }

        if (g == 0) {
            const float id = invdeg[node];
            float* __restrict__ srow = &xin[ln * STR + F + q * 8];
            *(float4*)srow = make_float4(a0.x * id, a0.y * id,
                                         a0.z * id, a0.w * id);
            *(float4*)(srow + 4) = make_float4(a1.x * id, a1.y * id,
                                               a1.z * id, a1.w * id);
        }
    }
    __syncthreads();

    // ---- phase C: linear ----
    const int j0 = __builtin_amdgcn_readfirstlane(wv * JT);

    float acc[JT];
#pragma unroll
    for (int j = 0; j < JT; ++j) acc[j] = b[j0 + j];

    const float* __restrict__ xrow = &xin[lane * STR];
#pragma unroll 2
    for (int k4 = 0; k4 < 32; ++k4) {
        const float4 xv = *(const float4*)&xrow[k4 * 4];
#pragma unroll
        for (int kk = 0; kk < 4; ++kk) {
            const int   k  = k4 * 4 + kk;
            const float xk = ((const float*)&xv)[kk];
#pragma unroll
            for (int j = 0; j < JT; ++j)
                acc[j] = fmaf(xk, W[k * OUT + j0 + j], acc[j]);
        }
    }

    const int node = node0 + lane;
    if (node < n_nodes) {
#pragma unroll
        for (int j = 0; j < JT; ++j) {
            float v = acc[j];
            if (RELU) v = fmaxf(v, 0.f);
            acc[j] = v;
        }
        if constexpr (OUT_BF16) {
            unsigned* __restrict__ hw =
                (unsigned*)(hb_out + (size_t)node * OUT + j0);
#pragma unroll
            for (int j = 0; j < JT; j += 2)
                hw[j >> 1] = bf16_rne(acc[j]) | (bf16_rne(acc[j + 1]) << 16);
        } else {
#pragma unroll
            for (int j = 0; j < JT; ++j)
                out[(size_t)node * OUT + j0 + j] = acc[j];
        }
    }
}

extern "C" void kernel_launch(void* const* d_in, const int* in_sizes, int n_in,
                              void* d_out, int out_size, void* d_ws, size_t ws_size,
                              hipStream_t stream)
{
    const float* in_feat   = (const float*)d_in[0];
    const float* edge_feat = (const float*)d_in[1];
    const int*   src       = (const int*)d_in[2];
    const int*   dst       = (const int*)d_in[3];
    const float* W1        = (const float*)d_in[4];
    const float* b1        = (const float*)d_in[5];
    const float* W2        = (const float*)d_in[6];
    const float* b2        = (const float*)d_in[7];
    float*       out       = (float*)d_out;

    const int n_nodes = in_sizes[0] / F;
    const int n_edges = in_sizes[2];
    const int nb      = (n_nodes + 63) >> 6;  // 64-node buckets

    // workspace layout (4-byte units)
    const int S = 100352;  // >= n_nodes+1, multiple of 256
    int*   wsi     = (int*)d_ws;
    int*   bcnt    = wsi;                     // [nb]
    int*   boff    = wsi + 2048;              // [nb+1]
    int*   bcursor = wsi + 4096;              // [nb]
    int*   off2    = wsi + 6144;              // [n_nodes+1]
    float* invdeg  = (float*)(wsi + 6144 + S);            // [n_nodes]
    int2*  brec    = (int2*)(wsi + 6144 + 2 * S);         // [n_edges]
    unsigned short* hb0 = (unsigned short*)(brec + (size_t)n_edges); // in_feat bf16
    unsigned short* hb1 = hb0 + (size_t)n_nodes * F;                  // h1 bf16

    hipMemsetAsync(bcnt, 0, (size_t)nb * sizeof(int), stream);

    const int egrid = (n_edges + EPB - 1) / EPB;
    bhist_kernel<<<egrid, TPB, 0, stream>>>(dst, bcnt, n_edges, nb);
    scan_kernel<<<1, 1024, 0, stream>>>(bcnt, boff, bcursor, nb);
    multisplit_kernel<<<egrid, TPB, 0, stream>>>(src, dst, edge_feat,
                                                 bcursor, brec, n_edges, nb);
    bucket_sort_kernel<<<nb, 256, 0, stream>>>(brec, boff, off2, invdeg,
                                               n_nodes, nb);

    const int n8    = (n_nodes * F) >> 3;
    const int cgrid = (n8 + 255) / 256;
    const int lgrid = (n_nodes + 63) / 64;

    f32_to_bf16_kernel<<<cgrid, 256, 0, stream>>>(in_feat, hb0, n8);

    // ---- layer 1: h = in_feat (fp32 staging), gather from hb0, emit hb1 ----
    gnn_layer_kernel<64, true, false, true><<<lgrid, 256, 0, stream>>>(
        in_feat, nullptr, hb0, brec, off2, invdeg, W1, b1, nullptr, hb1, n_nodes);

    // ---- layer 2: h = h1 (bf16 staging from hb1), gather from hb1 ----
    gnn_layer_kernel<32, false, true, false><<<lgrid, 256, 0, stream>>>(
        nullptr, hb1, hb1, brec, off2, invdeg, W2, b2, out, nullptr, n_nodes);
}

// Round 13
// 168.116 us; speedup vs baseline: 1.5049x; 1.5049x over previous
//
#include <hip/hip_runtime.h>
#include <hip/hip_bf16.h>

// ---------------------------------------------------------------------------
// CGNN: 2 layers of { m = h[src]*e ; s = segment_mean(m,dst) ;
//                     [h, h_N] @ W + b (+ relu on layer 1) }
// Round 12: revert r11 fusion (TLP loss). Back to r10 separate kernels, plus:
//   - padded per-bucket windows (PADBKT) -> bhist + scan + memset eliminated
//     (init_cursor sets bcursor[b] = b*PADBKT; multisplit appends; bucket_sort
//     compacts in place, emits off2/end2/invdeg, records carry src*128)
//   - agg v6: 2 nodes per wave (32 lanes each: 4 edge slots x 8 feat octets,
//     2 slots unrolled = 8 edges/node in flight) -> reduce 3->2 stages and
//     prologue/store shared by 2 nodes (~2x less fixed VALU overhead)
//   - linear_lds kernels unchanged (r9 win), bf16 gather table (r6 win)
// ---------------------------------------------------------------------------

#define F 64
#define NBMAX 2048          // bucket arrays sized for up to 2048 buckets
#define EPT 8               // edges per thread in multisplit
#define TPB 1024            // threads per block in multisplit
#define EPB (EPT * TPB)     // edges per block = 8192
#define PADBKT 1280         // padded window per bucket (mean 1024, +8 sigma)

__global__ __launch_bounds__(256) void init_cursor_kernel(
    int* __restrict__ bcursor, int nb)
{
    const int i = blockIdx.x * 256 + threadIdx.x;
    if (i < nb) bcursor[i] = i * PADBKT;
}

// Block-local multisplit into padded per-bucket windows: rank 8192 edges in
// LDS, reserve per-bucket ranges with one global atomic per non-empty bucket,
// write dense runs. rec.x = (local_dst << 20) | src, rec.y = bits(edge_feat).
__global__ __launch_bounds__(TPB) void multisplit_kernel(
    const int* __restrict__ src, const int* __restrict__ dst,
    const float* __restrict__ ef, int* __restrict__ bcursor,
    int2* __restrict__ brec, int n_edges, int nb)
{
    __shared__ int lcnt[NBMAX];
    __shared__ int lbase[NBMAX];
    const int tid = threadIdx.x;
    for (int i = tid; i < nb; i += TPB) lcnt[i] = 0;
    __syncthreads();

    const int e0 = blockIdx.x * EPB + tid;
    int d[EPT], rk[EPT];
#pragma unroll
    for (int k = 0; k < EPT; ++k) {
        const int e = e0 + k * TPB;
        const int dd = (e < n_edges) ? dst[e] : -1;
        d[k]  = dd;
        rk[k] = (dd >= 0) ? atomicAdd(&lcnt[dd >> 6], 1) : 0;
    }
    __syncthreads();
    for (int i = tid; i < nb; i += TPB) {
        const int c = lcnt[i];
        lbase[i] = c ? atomicAdd(&bcursor[i], c) : 0;
    }
    __syncthreads();
#pragma unroll
    for (int k = 0; k < EPT; ++k) {
        const int e = e0 + k * TPB;
        if (e < n_edges) {
            const int dd  = d[k];
            const int bkt = dd >> 6;
            const int pos = lbase[bkt] + rk[k];
            if (pos < (bkt + 1) * PADBKT)   // overflow guard (never with data)
                brec[pos] = make_int2(((dd & 63) << 20) | src[e],
                                      __float_as_int(ef[e]));
        }
    }
}

// Block per bucket: stage window records in LDS, 64-counter histogram + wave
// scan, compact back at exact per-node positions (front of window). Final
// records carry PRE-SCALED byte offsets (src*128). Emits off2/end2/invdeg.
__global__ __launch_bounds__(256) void bucket_sort_kernel(
    int2* __restrict__ brec, const int* __restrict__ bcursor,
    int* __restrict__ off2, int* __restrict__ end2,
    float* __restrict__ invdeg, int n_nodes)
{
    __shared__ int2 stage[PADBKT];
    __shared__ int  lcnt[64];
    __shared__ int  lcur[64];

    const int b   = blockIdx.x;
    const int tid = threadIdx.x;
    const int w0  = b * PADBKT;
    int cnt = bcursor[b] - w0;
    if (cnt > PADBKT) cnt = PADBKT;

    if (tid < 64) lcnt[tid] = 0;
    __syncthreads();

    for (int i = tid; i < cnt; i += 256) {
        const int2 r = brec[w0 + i];
        stage[i] = r;
        atomicAdd(&lcnt[r.x >> 20], 1);
    }
    __syncthreads();

    if (tid < 64) {
        const int c = lcnt[tid];
        int v = c;
        for (int d = 1; d < 64; d <<= 1) {
            int t = __shfl_up(v, d, 64);
            if (tid >= d) v += t;
        }
        const int excl = v - c;
        lcur[tid] = excl;
        const int node = (b << 6) + tid;
        if (node < n_nodes) {
            off2[node]   = w0 + excl;
            end2[node]   = w0 + excl + c;
            invdeg[node] = 1.0f / fmaxf((float)c, 1.0f);
        }
    }
    __syncthreads();

    for (int i = tid; i < cnt; i += 256) {
        const int2 r   = stage[i];
        const int  pos = atomicAdd(&lcur[r.x >> 20], 1);
        brec[w0 + pos] = make_int2((r.x & 0xFFFFF) << 7, r.y);  // byte offset
    }
}

__device__ __forceinline__ unsigned bf16_rne(float f)
{
    unsigned u = __float_as_uint(f);
    return (u + 0x7FFFu + ((u >> 16) & 1u)) >> 16;
}

// RNE-convert fp32 array to packed bf16 (8 elems / thread).
__global__ __launch_bounds__(256) void f32_to_bf16_kernel(
    const float* __restrict__ x, unsigned short* __restrict__ y, int n8)
{
    const int i = blockIdx.x * 256 + threadIdx.x;
    if (i >= n8) return;
    const float4 a = ((const float4*)x)[2 * i];
    const float4 b = ((const float4*)x)[2 * i + 1];
    uint4 o;
    o.x = bf16_rne(a.x) | (bf16_rne(a.y) << 16);
    o.y = bf16_rne(a.z) | (bf16_rne(a.w) << 16);
    o.z = bf16_rne(b.x) | (bf16_rne(b.y) << 16);
    o.w = bf16_rne(b.z) | (bf16_rne(b.w) << 16);
    ((uint4*)y)[i] = o;
}

// TWO nodes per wave: n = lane>>5 selects the node, within 32 lanes
// g = 0..3 edge slots x q = 0..7 feature octets. 2 slots unrolled
// (A = base+g, B = base+4+g) -> 8 edges/node in flight. rec.x = byte offset.
// Reduce over g: 2 shfl_xor stages (m=8,16) shared by both nodes.
__global__ __launch_bounds__(256) void agg_kernel(
    const unsigned short* __restrict__ hb, const int2* __restrict__ rec,
    const int* __restrict__ off, const int* __restrict__ end,
    const float* __restrict__ invdeg, float* __restrict__ s, int n_nodes)
{
    const int wid  = (blockIdx.x * 256 + threadIdx.x) >> 6;
    const int lane = threadIdx.x & 63;
    const int n    = lane >> 5;        // node select within wave
    const int r    = lane & 31;
    const int g    = r >> 3;           // 0..3 edge slot
    const int q    = r & 7;            // 0..7 feature octet

    const int  node   = wid * 2 + n;
    const bool active = node < n_nodes;
    const int  e0 = active ? off[node] : 0;
    const int  e1 = active ? end[node] : 0;

    const char* __restrict__ hq = (const char*)hb + q * 16;

    float4 aA0 = make_float4(0.f, 0.f, 0.f, 0.f);
    float4 aA1 = make_float4(0.f, 0.f, 0.f, 0.f);
    float4 aB0 = make_float4(0.f, 0.f, 0.f, 0.f);
    float4 aB1 = make_float4(0.f, 0.f, 0.f, 0.f);

    for (int base = e0; base < e1; base += 8) {
        const int  eA = base + g;
        const int  eB = base + 4 + g;
        const bool vA = eA < e1;
        const bool vB = eB < e1;
        const int2 rA = rec[vA ? eA : e0];
        const int2 rB = rec[vB ? eB : e0];
        const float evA = vA ? __int_as_float(rA.y) : 0.f;
        const float evB = vB ? __int_as_float(rB.y) : 0.f;
        const uint4 xA = *(const uint4*)(hq + rA.x);
        const uint4 xB = *(const uint4*)(hq + rB.x);

        aA0.x = fmaf(__uint_as_float(xA.x << 16),         evA, aA0.x);
        aA0.y = fmaf(__uint_as_float(xA.x & 0xFFFF0000u), evA, aA0.y);
        aA0.z = fmaf(__uint_as_float(xA.y << 16),         evA, aA0.z);
        aA0.w = fmaf(__uint_as_float(xA.y & 0xFFFF0000u), evA, aA0.w);
        aA1.x = fmaf(__uint_as_float(xA.z << 16),         evA, aA1.x);
        aA1.y = fmaf(__uint_as_float(xA.z & 0xFFFF0000u), evA, aA1.y);
        aA1.z = fmaf(__uint_as_float(xA.w << 16),         evA, aA1.z);
        aA1.w = fmaf(__uint_as_float(xA.w & 0xFFFF0000u), evA, aA1.w);

        aB0.x = fmaf(__uint_as_float(xB.x << 16),         evB, aB0.x);
        aB0.y = fmaf(__uint_as_float(xB.x & 0xFFFF0000u), evB, aB0.y);
        aB0.z = fmaf(__uint_as_float(xB.y << 16),         evB, aB0.z);
        aB0.w = fmaf(__uint_as_float(xB.y & 0xFFFF0000u), evB, aB0.w);
        aB1.x = fmaf(__uint_as_float(xB.z << 16),         evB, aB1.x);
        aB1.y = fmaf(__uint_as_float(xB.z & 0xFFFF0000u), evB, aB1.y);
        aB1.z = fmaf(__uint_as_float(xB.w << 16),         evB, aB1.z);
        aB1.w = fmaf(__uint_as_float(xB.w & 0xFFFF0000u), evB, aB1.w);
    }

    float4 a0 = make_float4(aA0.x + aB0.x, aA0.y + aB0.y,
                            aA0.z + aB0.z, aA0.w + aB0.w);
    float4 a1 = make_float4(aA1.x + aB1.x, aA1.y + aB1.y,
                            aA1.z + aB1.z, aA1.w + aB1.w);

    // reduce across g (m = 8, 16) — stays within each 32-lane node half
#pragma unroll
    for (int m = 8; m <= 16; m <<= 1) {
        a0.x += __shfl_xor(a0.x, m); a0.y += __shfl_xor(a0.y, m);
        a0.z += __shfl_xor(a0.z, m); a0.w += __shfl_xor(a0.w, m);
        a1.x += __shfl_xor(a1.x, m); a1.y += __shfl_xor(a1.y, m);
        a1.z += __shfl_xor(a1.z, m); a1.w += __shfl_xor(a1.w, m);
    }

    if (g == 0 && active) {
        const float id = invdeg[node];
        float* __restrict__ srow = s + (size_t)node * F + q * 8;
        *(float4*)srow = make_float4(a0.x * id, a0.y * id, a0.z * id, a0.w * id);
        *(float4*)(srow + 4) = make_float4(a1.x * id, a1.y * id, a1.z * id, a1.w * id);
    }
}

// Block = 64 nodes x 4 waves. Stage x = [h|s] rows into LDS with coalesced
// loads (h from fp32 or bf16 shadow per IN_BF16), s always fp32. Wave wv
// computes output cols [wv*JT, ...) for all 64 nodes (lane = node), reading
// x from LDS (ds_read_b128) and W via wave-uniform s_load.
// OUT_BF16: write only the bf16 shadow row (next layer's gather + lin input).
template <int OUT, bool RELU, bool IN_BF16, bool OUT_BF16>
__global__ __launch_bounds__(256) void linear_lds_kernel(
    const float* __restrict__ hin_f, const unsigned short* __restrict__ hin_b,
    const float* __restrict__ s,
    const float* __restrict__ W, const float* __restrict__ b,
    float* __restrict__ out, unsigned short* __restrict__ hb_out, int n_nodes)
{
    constexpr int JT  = OUT / 4;   // j-tile per wave: 16 (lin1) / 8 (lin2)
    constexpr int STR = 132;       // row stride in floats (128 + 4, 16B-aligned)
    __shared__ float xin[64 * STR];

    const int tid   = threadIdx.x;
    const int node0 = blockIdx.x * 64;

    if constexpr (IN_BF16) {
        for (int i = tid; i < 512; i += 256) {
            const int ln = i >> 3, c8 = i & 7;
            const int node = node0 + ln;
            uint4 v = make_uint4(0u, 0u, 0u, 0u);
            if (node < n_nodes)
                v = *(const uint4*)&hin_b[(size_t)node * F + c8 * 8];
            float4 lo = make_float4(__uint_as_float(v.x << 16),
                                    __uint_as_float(v.x & 0xFFFF0000u),
                                    __uint_as_float(v.y << 16),
                                    __uint_as_float(v.y & 0xFFFF0000u));
            float4 hi = make_float4(__uint_as_float(v.z << 16),
                                    __uint_as_float(v.z & 0xFFFF0000u),
                                    __uint_as_float(v.w << 16),
                                    __uint_as_float(v.w & 0xFFFF0000u));
            *(float4*)&xin[ln * STR + c8 * 8]     = lo;
            *(float4*)&xin[ln * STR + c8 * 8 + 4] = hi;
        }
    } else {
        for (int i = tid; i < 1024; i += 256) {
            const int ln = i >> 4, c4 = i & 15;
            const int node = node0 + ln;
            float4 v = make_float4(0.f, 0.f, 0.f, 0.f);
            if (node < n_nodes)
                v = *(const float4*)&hin_f[(size_t)node * F + c4 * 4];
            *(float4*)&xin[ln * STR + c4 * 4] = v;
        }
    }
    for (int i = tid; i < 1024; i += 256) {
        const int ln = i >> 4, c4 = i & 15;
        const int node = node0 + ln;
        float4 v = make_float4(0.f, 0.f, 0.f, 0.f);
        if (node < n_nodes) v = *(const float4*)&s[(size_t)node * F + c4 * 4];
        *(float4*)&xin[ln * STR + F + c4 * 4] = v;
    }
    __syncthreads();

    const int lane = tid & 63;
    const int j0   = __builtin_amdgcn_readfirstlane((tid >> 6) * JT);

    float acc[JT];
#pragma unroll
    for (int j = 0; j < JT; ++j) acc[j] = b[j0 + j];

    const float* __restrict__ xrow = &xin[lane * STR];
#pragma unroll 2
    for (int k4 = 0; k4 < 32; ++k4) {
        const float4 xv = *(const float4*)&xrow[k4 * 4];
#pragma unroll
        for (int kk = 0; kk < 4; ++kk) {
            const int   k  = k4 * 4 + kk;
            const float xk = ((const float*)&xv)[kk];
#pragma unroll
            for (int j = 0; j < JT; ++j)
                acc[j] = fmaf(xk, W[k * OUT + j0 + j], acc[j]);
        }
    }

    const int node = node0 + lane;
    if (node < n_nodes) {
#pragma unroll
        for (int j = 0; j < JT; ++j) {
            float v = acc[j];
            if (RELU) v = fmaxf(v, 0.f);
            acc[j] = v;
        }
        if constexpr (OUT_BF16) {
            unsigned* __restrict__ hw =
                (unsigned*)(hb_out + (size_t)node * OUT + j0);
#pragma unroll
            for (int j = 0; j < JT; j += 2)
                hw[j >> 1] = bf16_rne(acc[j]) | (bf16_rne(acc[j + 1]) << 16);
        } else {
#pragma unroll
            for (int j = 0; j < JT; ++j)
                out[(size_t)node * OUT + j0 + j] = acc[j];
        }
    }
}

extern "C" void kernel_launch(void* const* d_in, const int* in_sizes, int n_in,
                              void* d_out, int out_size, void* d_ws, size_t ws_size,
                              hipStream_t stream)
{
    const float* in_feat   = (const float*)d_in[0];
    const float* edge_feat = (const float*)d_in[1];
    const int*   src       = (const int*)d_in[2];
    const int*   dst       = (const int*)d_in[3];
    const float* W1        = (const float*)d_in[4];
    const float* b1        = (const float*)d_in[5];
    const float* W2        = (const float*)d_in[6];
    const float* b2        = (const float*)d_in[7];
    float*       out       = (float*)d_out;

    const int n_nodes = in_sizes[0] / F;
    const int n_edges = in_sizes[2];
    const int nb      = (n_nodes + 63) >> 6;  // 64-node buckets

    // workspace layout (4-byte units)
    const int S = 100352;  // >= n_nodes+1, multiple of 256
    int*   wsi     = (int*)d_ws;
    int*   bcursor = wsi;                                 // [nb]
    int*   off2    = wsi + 2048;                          // [n_nodes]
    int*   end2    = wsi + 2048 + S;                      // [n_nodes]
    float* invdeg  = (float*)(wsi + 2048 + 2 * S);        // [n_nodes]
    int2*  brec    = (int2*)(wsi + 2048 + 3 * S);         // [nb * PADBKT]
    float* s       = (float*)(brec + (size_t)nb * PADBKT);
    unsigned short* hb = (unsigned short*)(s + (size_t)n_nodes * F);

    const int egrid = (n_edges + EPB - 1) / EPB;
    init_cursor_kernel<<<(nb + 255) / 256, 256, 0, stream>>>(bcursor, nb);
    multisplit_kernel<<<egrid, TPB, 0, stream>>>(src, dst, edge_feat,
                                                 bcursor, brec, n_edges, nb);
    bucket_sort_kernel<<<nb, 256, 0, stream>>>(brec, bcursor, off2, end2,
                                               invdeg, n_nodes);

    const int n8    = (n_nodes * F) >> 3;
    const int cgrid = (n8 + 255) / 256;
    const int agrid = (n_nodes + 7) / 8;     // 2 nodes/wave, 4 waves/block
    const int lgrid = (n_nodes + 63) / 64;

    // ---- layer 1 ----
    f32_to_bf16_kernel<<<cgrid, 256, 0, stream>>>(in_feat, hb, n8);
    agg_kernel<<<agrid, 256, 0, stream>>>(hb, brec, off2, end2, invdeg, s, n_nodes);
    linear_lds_kernel<64, true, false, true><<<lgrid, 256, 0, stream>>>(
        in_feat, nullptr, s, W1, b1, nullptr, hb, n_nodes);

    // ---- layer 2 ----
    agg_kernel<<<agrid, 256, 0, stream>>>(hb, brec, off2, end2, invdeg, s, n_nodes);
    linear_lds_kernel<32, false, true, false><<<lgrid, 256, 0, stream>>>(
        nullptr, hb, s, W2, b2, out, nullptr, n_nodes);
}